// Round 10
// baseline (185.875 us; speedup 1.0000x reference)
//
#include <hip/hip_runtime.h>
#include <hip/hip_bf16.h>

// GATConv N=50000, C=64, H=12, E=400000 (+N self loops), x-space aggregation:
//   y[d] = concat_h[ (sum_e w_eh x[s_e]) / (den_h*H) ] @ Wstack,  h never built.
// R10: aggregation itself is MFMA'd. Per node (4 per wave, serial):
//   z[12x64] = Wmat[12 x K32] @ Xg[K32 x 64]  via 4x mfma_16x16x32_bf16,
//   den[12]  = Wmat @ Ones    via 1 more MFMA -- lands in the SAME (quad,r)
//   register layout as the accumulator, so normalization is element-wise.
//   Wl (A-frag layout [head][slot], stride 40 bf16 = 16B aligned) gets w in
//   bf16, zero past deg. Xg ([ch][slot], stride 40) staged by lane=(slot,
//   half): 4x b128 global loads (ALL deg rows in one memory round, no
//   readlane chain) + 32x b16 LDS scatter. Pad slots hold stale-finite data
//   (one-time zero at block start) annihilated by w=0. deg>32 (P~1e-10,
//   CAP=64) -> second K-pass accumulating into the same regs.
//   zt -> LDS, barrier, 16x64x768 MFMA GEMM + fused relu(x+y+bias).
// Kernels: k_pre (cnt=0 | Wt2 | Vt), k_main (adj build | ax-MFMA + xb),
// k_fused. Multi-dispatch (R8: cooperative grid.sync ~80us each -- never).
// No segment_max: exp(s)/sum exp(s) is exact here (logits O(few), fp32 exp).

typedef __bf16 bf16x8 __attribute__((ext_vector_type(8)));
typedef float  f32x4  __attribute__((ext_vector_type(4)));

#define HEADS 12
#define CH 64
#define HC 768
#define CAP 64
#define ACOLS 24      // a_all[n][0..11]=src logits, [12..23]=dst logits
#define ZSTRIDE 776   // zt row stride (bf16)
#define XSTR 40       // Xg/Wl row stride in bf16 (80B = 16B-aligned rows)

__global__ __launch_bounds__(256) void k_pre(
    const float* __restrict__ W,
    const float* __restrict__ att_src, const float* __restrict__ att_dst,
    int* __restrict__ cnt, __bf16* __restrict__ Wt2, __bf16* __restrict__ Vt,
    int N) {
    const int nb_z = (N + 255) >> 8;
    const int nb_w = (CH * HC) >> 8;           // 192
    int b = blockIdx.x, tid = threadIdx.x;
    if (b < nb_z) {                            // ---- cnt = 0 ----
        int i = b * 256 + tid;
        if (i < N) cnt[i] = 0;
        return;
    }
    b -= nb_z;
    if (b < nb_w) {                            // ---- Wt2 transpose ----
        int t = b * 256 + tid;
        int c = t / HC, kk = t % HC;
        int k = kk & 63;
        Wt2[t] = (__bf16)W[(size_t)k * HC + (kk - k) + c];
        return;
    }
    b -= nb_w;                                 // ---- Vt col b (0..31) ----
    if (b >= 2 * HEADS) {
        if (tid < CH) Vt[b * CH + tid] = (__bf16)0.f;
        return;
    }
    const float* att = (b < HEADS) ? att_src + b * CH
                                   : att_dst + (b - HEADS) * CH;
    int k = tid >> 2, cq = tid & 3;            // 64 k-rows x 4 c-quarters
    const float* wr = W + (size_t)k * HC + (b % HEADS) * CH + cq * 16;
    float s = 0.f;
#pragma unroll
    for (int j = 0; j < 16; ++j) s += wr[j] * att[cq * 16 + j];
    s += __shfl_xor(s, 1, 64);
    s += __shfl_xor(s, 2, 64);
    if (cq == 0) Vt[b * CH + k] = (__bf16)s;
}

__global__ __launch_bounds__(256) void k_main(
    const float* __restrict__ x, const int* __restrict__ ei,
    const __bf16* __restrict__ Vt,
    int* __restrict__ cnt, int* __restrict__ adj,
    __bf16* __restrict__ xb, float* __restrict__ a_all, int N, int E) {
    const int EP = E + N;
    const int nb_build = (EP + 255) >> 8;
    int b = blockIdx.x, tid = threadIdx.x;

    if (b < nb_build) {                        // ---- adjacency: SOURCE ids ----
        int e = b * 256 + tid;
        if (e < EP) {
            int d, s;
            if (e < E) { d = ei[E + e]; s = ei[e]; }
            else       { d = e - E;     s = d; }
            int pos = atomicAdd(&cnt[d], 1);
            if (pos < CAP) adj[d * CAP + pos] = s;
        }
        return;
    }
    b -= nb_build;                             // ---- a_all = x@V + xb ----
    int wave = tid >> 6, lane = tid & 63;
    int m = lane & 15, quad = lane >> 4;
    int m0 = b * 64 + wave * 16;
    int row = m0 + m;
    int rc = row < N ? row : N - 1;
    const float* xa = x + (size_t)rc * CH + quad * 8;
    f32x4 v0 = *(const f32x4*)xa;
    f32x4 v1 = *(const f32x4*)(xa + 4);
    f32x4 v2 = *(const f32x4*)(xa + 32);
    f32x4 v3 = *(const f32x4*)(xa + 36);
    bf16x8 a0, a1;
#pragma unroll
    for (int j = 0; j < 4; ++j) {
        a0[j] = (__bf16)v0[j]; a0[4 + j] = (__bf16)v1[j];
        a1[j] = (__bf16)v2[j]; a1[4 + j] = (__bf16)v3[j];
    }
    if (row < N) {                             // fused xb = bf16(x)
        *(bf16x8*)(xb + (size_t)row * CH + quad * 8) = a0;
        *(bf16x8*)(xb + (size_t)row * CH + quad * 8 + 32) = a1;
    }
#pragma unroll
    for (int t = 0; t < 2; ++t) {              // two 16-col tiles -> 24 cols
        const __bf16* bp = Vt + (size_t)(t * 16 + m) * CH + quad * 8;
        bf16x8 b0 = *(const bf16x8*)bp;
        bf16x8 b1 = *(const bf16x8*)(bp + 32);
        f32x4 acc = {0.f, 0.f, 0.f, 0.f};
        acc = __builtin_amdgcn_mfma_f32_16x16x32_bf16(a0, b0, acc, 0, 0, 0);
        acc = __builtin_amdgcn_mfma_f32_16x16x32_bf16(a1, b1, acc, 0, 0, 0);
        int col = t * 16 + m;
        if (col < ACOLS) {
#pragma unroll
            for (int r = 0; r < 4; ++r) {
                int rr = m0 + quad * 4 + r;
                if (rr < N) a_all[(size_t)rr * ACOLS + col] = acc[r];
            }
        }
    }
}

__global__ __launch_bounds__(256) void k_fused(
    const int* __restrict__ cnt, const int* __restrict__ adj,
    const float* __restrict__ a_all,
    const __bf16* __restrict__ xb, const __bf16* __restrict__ Wt2,
    const float* __restrict__ x, const float* __restrict__ bias,
    float* __restrict__ out, int N) {
    __shared__ __bf16 zt[16 * ZSTRIDE];        // 24.8 KB
    __shared__ __bf16 Xg[4][CH * XSTR];        // 20.5 KB  [wave][ch*40+slot]
    __shared__ __bf16 Wl[4][16 * XSTR];        //  5.1 KB  [wave][head*40+slot]
    int wave = threadIdx.x >> 6, lane = threadIdx.x & 63;
    int base = blockIdx.x * 16;

    // one-time zero (keeps pad slots finite forever; w=0 annihilates them)
    {
        int* p = (int*)Xg[wave];
        for (int i = lane; i < CH * XSTR / 2; i += 64) p[i] = 0;
        int* q = (int*)Wl[wave];
        for (int i = lane; i < 16 * XSTR / 2; i += 64) q[i] = 0;
    }

    // prologue: 4 nodes' cnt + adj[0..31] in parallel
    int degj[4], slj[4];
#pragma unroll
    for (int j = 0; j < 4; ++j) {
        int d = base + wave * 4 + j;
        int dg = cnt[d];
        degj[j] = dg < CAP ? dg : CAP;
        slj[j] = (lane < 32) ? adj[d * CAP + lane] : 0;   // poison past deg
    }

    bf16x8 onesb;
#pragma unroll
    for (int j = 0; j < 8; ++j) onesb[j] = (__bf16)1.0f;

    int m = lane & 15, quad = lane >> 4;
    int slot = lane >> 1, half = lane & 1;

    for (int j = 0; j < 4; ++j) {
        int row = wave * 4 + j;
        int d = base + row;
        int deg = degj[j];

        float adf[HEADS];
        {
            const f32x4* p = (const f32x4*)(a_all + (size_t)d * ACOLS + HEADS);
            f32x4 t0 = p[0], t1 = p[1], t2 = p[2];
#pragma unroll
            for (int u = 0; u < 4; ++u) { adf[u] = t0[u]; adf[4 + u] = t1[u]; adf[8 + u] = t2[u]; }
        }

        f32x4 acc[4], den;
#pragma unroll
        for (int t = 0; t < 4; ++t) acc[t] = (f32x4){0.f, 0.f, 0.f, 0.f};
        den = (f32x4){0.f, 0.f, 0.f, 0.f};

        int nkh = (deg > 32) ? 2 : 1;
        for (int kh = 0; kh < nkh; ++kh) {
            int sb = kh * 32;
            int ch_cnt = deg - sb; ch_cnt = ch_cnt > 32 ? 32 : ch_cnt;

            // ---- weights: lane = slot (0..31) ----
            int s_w = (kh == 0) ? slj[j]
                                : ((lane < 32) ? adj[d * CAP + 32 + lane] : 0);
            float wv[HEADS];
#pragma unroll
            for (int hh = 0; hh < HEADS; ++hh) wv[hh] = 0.f;
            if (lane < ch_cnt) {
                const f32x4* p = (const f32x4*)(a_all + (size_t)s_w * ACOLS);
                f32x4 t0 = p[0], t1 = p[1], t2 = p[2];
                float asf[HEADS];
#pragma unroll
                for (int u = 0; u < 4; ++u) { asf[u] = t0[u]; asf[4 + u] = t1[u]; asf[8 + u] = t2[u]; }
#pragma unroll
                for (int hh = 0; hh < HEADS; ++hh) {
                    float sc = asf[hh] + adf[hh];
                    sc = sc > 0.f ? sc : 0.2f * sc;
                    wv[hh] = __expf(sc);
                }
            }
            if (lane < 32) {
                __bf16* wrow = Wl[wave];
#pragma unroll
                for (int hh = 0; hh < HEADS; ++hh)
                    wrow[hh * XSTR + lane] = (__bf16)wv[hh];
            }

            // ---- staging: lane = (slot, half); all rows in one round ----
            if (slot < ch_cnt) {
                int ss = adj[d * CAP + sb + slot];        // valid: slot < deg
                const bf16x8* src = (const bf16x8*)(xb + (size_t)ss * CH + half * 32);
                bf16x8 v0 = src[0], v1 = src[1], v2 = src[2], v3 = src[3];
                __bf16* xg = Xg[wave];
                int chb = half * 32;
#pragma unroll
                for (int c = 0; c < 8; ++c) {
                    xg[(chb + c) * XSTR + slot]      = v0[c];
                    xg[(chb + 8 + c) * XSTR + slot]  = v1[c];
                    xg[(chb + 16 + c) * XSTR + slot] = v2[c];
                    xg[(chb + 24 + c) * XSTR + slot] = v3[c];
                }
            }

            // ---- fragments + MFMA (wave-internal; compiler inserts lgkmcnt) ----
            bf16x8 afrag = *(const bf16x8*)(Wl[wave] + m * XSTR + quad * 8);
            den = __builtin_amdgcn_mfma_f32_16x16x32_bf16(afrag, onesb, den, 0, 0, 0);
#pragma unroll
            for (int t = 0; t < 4; ++t) {
                bf16x8 bfrag = *(const bf16x8*)(Xg[wave] + (t * 16 + m) * XSTR + quad * 8);
                acc[t] = __builtin_amdgcn_mfma_f32_16x16x32_bf16(afrag, bfrag, acc[t], 0, 0, 0);
            }
        }

        // ---- normalize + zt write; lane holds head=quad*4+r, ch=t*16+m ----
        if (quad < 3) {
            __bf16* zr = zt + row * ZSTRIDE;
#pragma unroll
            for (int r = 0; r < 4; ++r) {
                int head = quad * 4 + r;
                float inv = 1.0f / ((den[r] + 1e-16f) * HEADS);
#pragma unroll
                for (int t = 0; t < 4; ++t)
                    zr[head * CH + t * 16 + m] = (__bf16)(acc[t][r] * inv);
            }
        }
    }

    __syncthreads();

    // ---- final 16x64x768 GEMM; wave = one 16-col tile ----
    {
        int n0 = wave * 16;
        const __bf16* za = zt + m * ZSTRIDE + quad * 8;
        const __bf16* wb = Wt2 + (size_t)(n0 + m) * HC + quad * 8;
        f32x4 acc = {0.f, 0.f, 0.f, 0.f};
#pragma unroll
        for (int kc = 0; kc < HC; kc += 32) {
            bf16x8 a  = *(const bf16x8*)(za + kc);
            bf16x8 bf = *(const bf16x8*)(wb + kc);
            acc = __builtin_amdgcn_mfma_f32_16x16x32_bf16(a, bf, acc, 0, 0, 0);
        }
        int col = n0 + m;
        float bv = bias[col];
#pragma unroll
        for (int r = 0; r < 4; ++r) {
            int dd = base + quad * 4 + r;
            if (dd < N) {
                float o = x[(size_t)dd * CH + col] + acc[r] + bv;
                out[(size_t)dd * CH + col] = fmaxf(o, 0.f);
            }
        }
    }
}

extern "C" void kernel_launch(void* const* d_in, const int* in_sizes, int n_in,
                              void* d_out, int out_size, void* d_ws, size_t ws_size,
                              hipStream_t stream) {
    const float* x       = (const float*)d_in[0];
    const int*   ei      = (const int*)d_in[1];
    const float* W       = (const float*)d_in[2];
    const float* att_src = (const float*)d_in[3];
    const float* att_dst = (const float*)d_in[4];
    const float* bias    = (const float*)d_in[5];
    float* out = (float*)d_out;

    int N = in_sizes[0] / CH;   // 50000
    int E = in_sizes[1] / 2;    // 400000
    int EP = E + N;

    char* ws = (char*)d_ws;
    size_t off = 0;
    auto take = [&](size_t bytes) -> void* {
        void* p = ws + off;
        off = (off + bytes + 255) & ~(size_t)255;
        return p;
    };
    __bf16* xb    = (__bf16*)take((size_t)N * CH * sizeof(__bf16));
    __bf16* Wt2   = (__bf16*)take((size_t)CH * HC * sizeof(__bf16));
    __bf16* Vt    = (__bf16*)take((size_t)32 * CH * sizeof(__bf16));
    float*  a_all = (float*)take((size_t)N * ACOLS * sizeof(float));
    int*    adj   = (int*)take((size_t)N * CAP * sizeof(int));
    int*    cnt   = (int*)take((size_t)N * sizeof(int));

    const int nb_z     = (N + 255) / 256;
    const int nb_w     = (CH * HC) / 256;
    const int nb_build = (EP + 255) / 256;
    const int nb_ax    = (N + 63) / 64;

    k_pre<<<nb_z + nb_w + 32, 256, 0, stream>>>(W, att_src, att_dst, cnt, Wt2, Vt, N);
    k_main<<<nb_build + nb_ax, 256, 0, stream>>>(x, ei, Vt, cnt, adj, xb, a_all, N, E);
    k_fused<<<(N + 15) / 16, 256, 0, stream>>>(cnt, adj, a_all, xb, Wt2, x, bias, out, N);
}